// Round 7
// baseline (194.306 us; speedup 1.0000x reference)
//
#include <hip/hip_runtime.h>

typedef unsigned short u16;
typedef unsigned int u32;

#define C_DIM 192
#define N_TOK 16384
#define M_LEN 256
#define HD 32
#define NH 6

#define AF_STRIDE 3080   // u16 per-token-tile A-frag region (6*512 + 8 skew)
#define LN2_BLOCKS 256   // 4 rows/block * 256 = 1024 rows

typedef __attribute__((ext_vector_type(8))) short short8v;
typedef __attribute__((ext_vector_type(4))) float float4v;

// Hardware bf16 convert: 2 f32 -> packed 2x bf16 (RNE), 1 instruction.
__device__ __forceinline__ u32 cvt_pk_bf16(float lo, float hi) {
    u32 r;
    asm("v_cvt_pk_bf16_f32 %0, %1, %2" : "=v"(r) : "v"(lo), "v"(hi));
    return r;
}
__device__ __forceinline__ u16 f2bf_hw(float f) {
    return (u16)cvt_pk_bf16(f, f);
}

// ---- shared device helper: one 192x192 weight block -> 4 fragments --------
__device__ __forceinline__ void wprep_block(
    const float* __restrict__ W, u16* __restrict__ outp, int bb, int tid)
{
    int gt = bb * 256 + tid;
    int f = gt >> 6, lane = gt & 63;
    int q8 = lane >> 4, ln = lane & 15;
    int wv = f / 18, r = f % 18;
    int kt = r / 3, jj = r % 3;
    const float* w0 = W + (kt * 32 + q8 * 8) * C_DIM + (wv * 3 + jj) * 16 + ln;
    union { u32 w[4]; short8v v; } out;
#pragma unroll
    for (int j = 0; j < 4; ++j)
        out.w[j] = cvt_pk_bf16(w0[(2 * j) * C_DIM], w0[(2 * j + 1) * C_DIM]);
    *(short8v*)&outp[f * 512 + lane * 8] = out.v;
}

// ---------------- Kernel W (fallback): Wq/Wp -> fragment-ordered bf16 ------
__global__ __launch_bounds__(256) void w_prep2(
    const float* __restrict__ Wq, u16* __restrict__ WqF,
    const float* __restrict__ Wp, u16* __restrict__ WpF)
{
    int bb = blockIdx.x;
    wprep_block((bb < 18) ? Wq : Wp, (bb < 18) ? WqF : WpF, bb % 18, threadIdx.x);
}

// ---------------- Kernel P: combined LN2+KV (4 rows/block) + weight prep ---
// blocks [0,256): ln2_kv, 4 rows each. blocks [256,292): Wq/Wp frag prep.
__global__ __launch_bounds__(256) void prep_combo(
    const float* __restrict__ prior, const float* __restrict__ g,
    const float* __restrict__ beta, const float* __restrict__ Wkv,
    u16* __restrict__ KfG, u16* __restrict__ VfG,
    const float* __restrict__ Wq, u16* __restrict__ WqF,
    const float* __restrict__ Wp, u16* __restrict__ WpF)
{
    int tid = threadIdx.x;
    if (blockIdx.x >= LN2_BLOCKS) {
        int bb = blockIdx.x - LN2_BLOCKS;   // 0..35
        wprep_block((bb < 18) ? Wq : Wp, (bb < 18) ? WqF : WpF, bb % 18, tid);
        return;
    }
    __shared__ float pr[4][C_DIM];
    __shared__ float red[4][3][2];
    int row0 = blockIdx.x * 4;
    float val[4];
    if (tid < 192) {
        int wv = tid >> 6;
#pragma unroll
        for (int i = 0; i < 4; ++i) {
            val[i] = prior[(row0 + i) * C_DIM + tid];
            float s1 = val[i], s2 = val[i] * val[i];
#pragma unroll
            for (int m = 1; m < 64; m <<= 1) {
                s1 += __shfl_xor(s1, m);
                s2 += __shfl_xor(s2, m);
            }
            if ((tid & 63) == 0) { red[i][wv][0] = s1; red[i][wv][1] = s2; }
        }
    }
    __syncthreads();
    if (tid < 192) {
#pragma unroll
        for (int i = 0; i < 4; ++i) {
            float a  = red[i][0][0] + red[i][1][0] + red[i][2][0];
            float c2 = red[i][0][1] + red[i][1][1] + red[i][2][1];
            float mu = a * (1.f / C_DIM);
            float rs = rsqrtf(c2 * (1.f / C_DIM) - mu * mu + 1e-5f);
            pr[i][tid] = (val[i] - mu) * rs * g[tid] + beta[tid];
        }
    }
    __syncthreads();
    if (tid >= 192) return;

    // 4 rows x (k,v) with 2-way partial sums: 16 indep FMA per 4 Wkv loads.
    float ka0[4] = {0,0,0,0}, ka1[4] = {0,0,0,0};
    float va0[4] = {0,0,0,0}, va1[4] = {0,0,0,0};
    for (int c = 0; c < C_DIM; c += 2) {
        float w0k = Wkv[c * 384 + tid];
        float w1k = Wkv[(c + 1) * 384 + tid];
        float w0v = Wkv[c * 384 + 192 + tid];
        float w1v = Wkv[(c + 1) * 384 + 192 + tid];
#pragma unroll
        for (int i = 0; i < 4; ++i) {
            float p0 = pr[i][c], p1 = pr[i][c + 1];
            ka0[i] = fmaf(p0, w0k, ka0[i]);
            ka1[i] = fmaf(p1, w1k, ka1[i]);
            va0[i] = fmaf(p0, w0v, va0[i]);
            va1[i] = fmaf(p1, w1v, va1[i]);
        }
    }
    int h = tid >> 5, dim = tid & 31;
#pragma unroll
    for (int i = 0; i < 4; ++i) {
        int row = row0 + i;
        int b = row >> 8, m = row & 255;
        int bh = b * NH + h;
        int kt = m >> 4, r = m & 15;
        float ka = ka0[i] + ka1[i];
        float va = va0[i] + va1[i];
        {
            int qd = dim >> 3, j = dim & 7;
            KfG[bh * 8192 + kt * 512 + (qd * 16 + r) * 8 + j] =
                f2bf_hw(ka * 0.17677669529663687f);
        }
        {
            int qd = r >> 2, reg = r & 3;
            int P = kt >> 1;
            int j = reg + 4 * (kt & 1);
            int dh = dim >> 4, n = dim & 15;
            VfG[bh * 8192 + (P * 2 + dh) * 512 + (qd * 16 + n) * 8 + j] = f2bf_hw(va);
        }
    }
}

// ---------------- Kernel A: LN1 + Q projection via MFMA ----------------
__global__ __launch_bounds__(256) void ln1_q_mfma(
    const float* __restrict__ x, const float* __restrict__ g,
    const float* __restrict__ beta, const u16* __restrict__ WqF,
    u16* __restrict__ q)
{
    __shared__ u16 Af[4 * AF_STRIDE];
    __shared__ u16 Tq[64 * 200];
    __shared__ float part[64][4][2];
    __shared__ float mu_s[64], rs_s[64];
    int b = blockIdx.x >> 8;
    int n0 = (blockIdx.x & 255) * 64;
    int t = threadIdx.x;
    int wv = t >> 6, lane = t & 63;

    float xv[48];
    {
        const float* xb = x + (((size_t)(b * C_DIM + wv * 48)) << 14) + n0 + lane;
        float s1p[4] = {0,0,0,0}, s2p[4] = {0,0,0,0};
#pragma unroll
        for (int i = 0; i < 48; ++i) {
            float f = xb[(size_t)i << 14];
            xv[i] = f;
            s1p[i & 3] += f;
            s2p[i & 3] += f * f;
        }
        part[lane][wv][0] = (s1p[0] + s1p[1]) + (s1p[2] + s1p[3]);
        part[lane][wv][1] = (s2p[0] + s2p[1]) + (s2p[2] + s2p[3]);
    }
    __syncthreads();
    if (t < 64) {
        float a  = part[t][0][0] + part[t][1][0] + part[t][2][0] + part[t][3][0];
        float c2 = part[t][0][1] + part[t][1][1] + part[t][2][1] + part[t][3][1];
        float mu = a * (1.f / C_DIM);
        mu_s[t] = mu;
        rs_s[t] = rsqrtf(c2 * (1.f / C_DIM) - mu * mu + 1e-5f);
    }
    __syncthreads();

    {
        float mu = mu_s[lane], rs = rs_s[lane];
        int mt2 = lane >> 4, ln2 = lane & 15;
        u32* A32 = (u32*)Af;
#pragma unroll
        for (int i = 0; i < 48; i += 2) {
            int c = wv * 48 + i;
            float f0 = (xv[i]     - mu) * rs * g[c]     + beta[c];
            float f1 = (xv[i + 1] - mu) * rs * g[c + 1] + beta[c + 1];
            int kt = c >> 5, k8 = (c & 31) >> 3, j = c & 7;
            A32[(mt2 * AF_STRIDE + kt * 512 + k8 * 128 + ln2 * 8 + j) >> 1] =
                cvt_pk_bf16(f0, f1);
        }
    }
    __syncthreads();

    int q8 = lane >> 4, ln = lane & 15;
    short8v Bf[18];
#pragma unroll
    for (int i = 0; i < 18; ++i)
        Bf[i] = *(const short8v*)&WqF[(wv * 18 + i) * 512 + lane * 8];

#pragma unroll
    for (int mt = 0; mt < 4; ++mt) {
        float4v acc[3] = {{0.f,0.f,0.f,0.f},{0.f,0.f,0.f,0.f},{0.f,0.f,0.f,0.f}};
#pragma unroll
        for (int kt = 0; kt < 6; ++kt) {
            short8v a = *(const short8v*)&Af[mt * AF_STRIDE + kt * 512 + lane * 8];
#pragma unroll
            for (int jj = 0; jj < 3; ++jj)
                acc[jj] = __builtin_amdgcn_mfma_f32_16x16x32_bf16(a, Bf[kt * 3 + jj], acc[jj], 0, 0, 0);
        }
#pragma unroll
        for (int jj = 0; jj < 3; ++jj)
#pragma unroll
            for (int r = 0; r < 4; ++r)
                Tq[(mt * 16 + q8 * 4 + r) * 200 + (wv * 3 + jj) * 16 + ln] = f2bf_hw(acc[jj][r]);
    }
    __syncthreads();

    {
        int tok = t >> 2, pp = t & 3;
        const uint4* src = (const uint4*)&Tq[tok * 200 + pp * 48];
        uint4* dst = (uint4*)(q + ((size_t)(b * N_TOK + n0 + tok)) * C_DIM + pp * 48);
#pragma unroll
        for (int i = 0; i < 6; ++i) dst[i] = src[i];
    }
}

// ---------------- Kernel B (fallback): LN2+KV, 1 row/block -----------------
__global__ __launch_bounds__(192) void ln2_kv_frag(
    const float* __restrict__ prior, const float* __restrict__ g,
    const float* __restrict__ beta, const float* __restrict__ Wkv,
    u16* __restrict__ KfG, u16* __restrict__ VfG)
{
    __shared__ float pr[C_DIM];
    __shared__ float red[3][2];
    int row = blockIdx.x;
    int tid = threadIdx.x;
    int wv = tid >> 6;
    float val = prior[row * C_DIM + tid];
    float s1 = val, s2 = val * val;
#pragma unroll
    for (int m = 1; m < 64; m <<= 1) {
        s1 += __shfl_xor(s1, m);
        s2 += __shfl_xor(s2, m);
    }
    if ((tid & 63) == 0) { red[wv][0] = s1; red[wv][1] = s2; }
    __syncthreads();
    float a  = red[0][0] + red[1][0] + red[2][0];
    float c2 = red[0][1] + red[1][1] + red[2][1];
    float mu = a * (1.f / C_DIM);
    float rs = rsqrtf(c2 * (1.f / C_DIM) - mu * mu + 1e-5f);
    pr[tid] = (val - mu) * rs * g[tid] + beta[tid];
    __syncthreads();
    float ka = 0.f, va = 0.f;
    for (int c = 0; c < C_DIM; ++c) {
        float p = pr[c];
        ka += p * Wkv[c * 384 + tid];
        va += p * Wkv[c * 384 + 192 + tid];
    }
    int b = row >> 8, m = row & 255;
    int h = tid >> 5, dim = tid & 31;
    int bh = b * NH + h;
    int kt = m >> 4, r = m & 15;
    {
        int qd = dim >> 3, j = dim & 7;
        KfG[bh * 8192 + kt * 512 + (qd * 16 + r) * 8 + j] =
            f2bf_hw(ka * 0.17677669529663687f);
    }
    {
        int qd = r >> 2, reg = r & 3;
        int P = kt >> 1;
        int j = reg + 4 * (kt & 1);
        int dh = dim >> 4, n = dim & 15;
        VfG[bh * 8192 + (P * 2 + dh) * 512 + (qd * 16 + n) * 8 + j] = f2bf_hw(va);
    }
}

// ---------------- Kernel C+D fused v5: K/V in regs + tree softmax ----------
// grid: 1024, 384 threads (wave = head). v5: tree-reduced max & sum (serial
// 64-add chain -> depth ~6), PV split into even/odd-P accumulator pairs
// (4 interleaved MFMA chains).
__global__ __launch_bounds__(384, 2) void attn_proj_fused(
    const u16* __restrict__ q, const u16* __restrict__ KfG,
    const u16* __restrict__ VfG, const u16* __restrict__ WpF,
    const float* __restrict__ bp, const float* __restrict__ x,
    float* __restrict__ y)
{
    __shared__ float Tf[C_DIM * 68];       // 52224 B; first 25600 B alias att tile
    u16* att_lds = (u16*)Tf;               // [64 tokens][stride 200] u16
    int b  = blockIdx.x >> 8;
    int n0 = (blockIdx.x & 255) * 64;
    int t = threadIdx.x;
    int wave = t >> 6, lane = t & 63;      // wave = head (0..5)
    int quad = lane >> 4, ln = lane & 15;
    const float LOG2E = 1.4426950408889634f;

    // ---- prologue: K/V fragments of THIS wave's head into registers ----
    int h = wave;
    short8v k_r[16], v_r[16];
    {
        const u16* Kf = KfG + (b * NH + h) * 8192;
        const u16* Vf = VfG + (b * NH + h) * 8192;
#pragma unroll
        for (int kt = 0; kt < 16; ++kt)
            k_r[kt] = *(const short8v*)&Kf[kt * 512 + lane * 8];
#pragma unroll
        for (int kt = 0; kt < 16; ++kt)
            v_r[kt] = *(const short8v*)&Vf[kt * 512 + lane * 8];
    }

    // ---- attention phase: 4 reps x 16 tokens, all state in registers ----
    {
        const u16* qbase = q + ((size_t)(b * N_TOK + n0 + ln)) * C_DIM + h * HD + quad * 8;
        short8v qnext = *(const short8v*)qbase;   // rep-0 prefetch

        for (int rep = 0; rep < 4; ++rep) {
            short8v qf = qnext;
            int nrep = rep < 3 ? rep + 1 : 3;
            qnext = *(const short8v*)(qbase + (size_t)nrep * 16 * C_DIM);

            float4v s[16];
#pragma unroll
            for (int kt = 0; kt < 16; ++kt) {
                float4v z = {0.f, 0.f, 0.f, 0.f};
                s[kt] = __builtin_amdgcn_mfma_f32_16x16x32_bf16(k_r[kt], qf, z, 0, 0, 0);
            }

            // tree max: 16 independent per-kt maxes, then 4-level tree
            float mk[16];
#pragma unroll
            for (int kt = 0; kt < 16; ++kt)
                mk[kt] = fmaxf(fmaxf(s[kt][0], s[kt][1]), fmaxf(s[kt][2], s[kt][3]));
#pragma unroll
            for (int st = 8; st >= 1; st >>= 1)
#pragma unroll
                for (int i = 0; i < st; ++i) mk[i] = fmaxf(mk[i], mk[i + st]);
            float mx = fmaxf(mk[0], __shfl_xor(mk[0], 16));
            mx = fmaxf(mx, __shfl_xor(mx, 32));

            // exp2 + per-kt partial sums + 4-level tree (depth ~6 vs 64)
            float nm = -mx * LOG2E;
            float lk[16];
#pragma unroll
            for (int kt = 0; kt < 16; ++kt) {
                float p0 = __builtin_amdgcn_exp2f(fmaf(s[kt][0], LOG2E, nm));
                float p1 = __builtin_amdgcn_exp2f(fmaf(s[kt][1], LOG2E, nm));
                float p2 = __builtin_amdgcn_exp2f(fmaf(s[kt][2], LOG2E, nm));
                float p3 = __builtin_amdgcn_exp2f(fmaf(s[kt][3], LOG2E, nm));
                s[kt][0] = p0; s[kt][1] = p1; s[kt][2] = p2; s[kt][3] = p3;
                lk[kt] = (p0 + p1) + (p2 + p3);
            }
#pragma unroll
            for (int st = 8; st >= 1; st >>= 1)
#pragma unroll
                for (int i = 0; i < st; ++i) lk[i] += lk[i + st];
            float l = lk[0] + __shfl_xor(lk[0], 16);
            l += __shfl_xor(l, 32);
            float inv = __builtin_amdgcn_rcpf(l);

            // PV: even/odd P accumulator pairs -> 4 interleaved MFMA chains
            float4v o0a = {0.f,0.f,0.f,0.f}, o0b = {0.f,0.f,0.f,0.f};
            float4v o1a = {0.f,0.f,0.f,0.f}, o1b = {0.f,0.f,0.f,0.f};
#pragma unroll
            for (int P = 0; P < 8; ++P) {
                union { u32 w[4]; short8v v; } pf;
                pf.w[0] = cvt_pk_bf16(s[2 * P][0],     s[2 * P][1]);
                pf.w[1] = cvt_pk_bf16(s[2 * P][2],     s[2 * P][3]);
                pf.w[2] = cvt_pk_bf16(s[2 * P + 1][0], s[2 * P + 1][1]);
                pf.w[3] = cvt_pk_bf16(s[2 * P + 1][2], s[2 * P + 1][3]);
                if (P & 1) {
                    o0b = __builtin_amdgcn_mfma_f32_16x16x32_bf16(pf.v, v_r[2 * P],     o0b, 0, 0, 0);
                    o1b = __builtin_amdgcn_mfma_f32_16x16x32_bf16(pf.v, v_r[2 * P + 1], o1b, 0, 0, 0);
                } else {
                    o0a = __builtin_amdgcn_mfma_f32_16x16x32_bf16(pf.v, v_r[2 * P],     o0a, 0, 0, 0);
                    o1a = __builtin_amdgcn_mfma_f32_16x16x32_bf16(pf.v, v_r[2 * P + 1], o1a, 0, 0, 0);
                }
            }
            float4v o0 = o0a + o0b;
            float4v o1 = o1a + o1b;

#pragma unroll
            for (int r = 0; r < 4; ++r) {
                float invr = __shfl(inv, quad * 4 + r);
                u16* rw = &att_lds[(rep * 16 + quad * 4 + r) * 200 + h * HD];
                rw[ln]      = f2bf_hw(o0[r] * invr);
                rw[16 + ln] = f2bf_hw(o1[r] * invr);
            }
        }
    }
    __syncthreads();

    // ---- x prefetch for epilogue (K/V regs dead; 32 regs free) ----
    float4 xu[8];
    {
        int r0 = t >> 4, p = t & 15;
#pragma unroll
        for (int pass = 0; pass < 8; ++pass) {
            int c = pass * 24 + r0;
            xu[pass] = ((const float4*)(x + (((size_t)(b * C_DIM + c)) << 14) + n0))[p];
        }
    }

    // ---- proj MFMA phase: wave w owns column-frags {2w, 2w+1} x 4 token-tiles
    short8v Bf[12];
#pragma unroll
    for (int jc = 0; jc < 2; ++jc) {
        int cf = wave * 2 + jc;            // 0..11
        int wv = cf / 3, jj = cf % 3;
#pragma unroll
        for (int kt = 0; kt < 6; ++kt)
            Bf[jc * 6 + kt] = *(const short8v*)&WpF[(wv * 18 + kt * 3 + jj) * 512 + lane * 8];
    }

    float4v acc[4][2];
#pragma unroll
    for (int mt = 0; mt < 4; ++mt) {
#pragma unroll
        for (int jc = 0; jc < 2; ++jc) {
            float4v z = {0.f, 0.f, 0.f, 0.f};
            acc[mt][jc] = z;
        }
#pragma unroll
        for (int kt = 0; kt < 6; ++kt) {
            short8v a = *(const short8v*)&att_lds[(mt * 16 + ln) * 200 + quad * 8 + kt * 32];
#pragma unroll
            for (int jc = 0; jc < 2; ++jc)
                acc[mt][jc] = __builtin_amdgcn_mfma_f32_16x16x32_bf16(a, Bf[jc * 6 + kt], acc[mt][jc], 0, 0, 0);
        }
    }
    __syncthreads();   // att tile dead; region reused as Tf

#pragma unroll
    for (int mt = 0; mt < 4; ++mt)
#pragma unroll
        for (int jc = 0; jc < 2; ++jc) {
            int c = (wave * 2 + jc) * 16 + ln;
#pragma unroll
            for (int r = 0; r < 4; ++r)
                Tf[c * 68 + mt * 16 + quad * 4 + r] = acc[mt][jc][r];
        }
    __syncthreads();

    // ---- epilogue: 384 threads, 8 passes x 24 channels, coalesced ----
    {
        int r0 = t >> 4;      // 0..23
        int p  = t & 15;
#pragma unroll
        for (int pass = 0; pass < 8; ++pass) {
            int c = pass * 24 + r0;
            float bias = bp[c];
            float4 a = *(const float4*)&Tf[c * 68 + p * 4];
            float4*       yr = (float4*)(y + (((size_t)(b * C_DIM + c)) << 14) + n0);
            float4 u = xu[pass];
            float4 w;
            w.x = a.x + bias + u.x;
            w.y = a.y + bias + u.y;
            w.z = a.z + bias + u.z;
            w.w = a.w + bias + u.w;
            yr[p] = w;
        }
    }
}

// ---------------- Fallback kernels (round-2 pipeline) ----------------
__global__ __launch_bounds__(256) void attn_mfma_kernel(
    const u16* __restrict__ q, const u16* __restrict__ KfG,
    const u16* __restrict__ VfG, u16* __restrict__ att)
{
    __shared__ u16 sh[16384];
    int tb = blockIdx.x & 63;
    int bh = blockIdx.x >> 6;
    int h = bh % NH, b = bh / NH;
    int tid = threadIdx.x;
    int wave = tid >> 6, lane = tid & 63;
    int quad = lane >> 4, ln = lane & 15;

    const u16* qbase = q + ((size_t)(b * N_TOK + tb * 256 + wave * 16 + ln)) * C_DIM
                         + h * HD + quad * 8;
    short8v qnext = *(const short8v*)qbase;

    {
        const uint4* Ks = (const uint4*)(KfG + bh * 8192);
        const uint4* Vs = (const uint4*)(VfG + bh * 8192);
        uint4* d = (uint4*)sh;
#pragma unroll
        for (int i = tid; i < 2048; i += 256)
            d[i] = (i < 1024) ? Ks[i] : Vs[i - 1024];
    }
    __syncthreads();

    const u16* Kf = sh;
    const u16* Vf = sh + 8192;
    const float LOG2E = 1.4426950408889634f;

    for (int rep = 0; rep < 4; ++rep) {
        short8v qf = qnext;
        int nrep = rep < 3 ? rep + 1 : 3;
        qnext = *(const short8v*)(qbase + (size_t)nrep * 64 * C_DIM);

        float4v s[16];
#pragma unroll
        for (int kt = 0; kt < 16; ++kt) {
            short8v kf = *(const short8v*)&Kf[kt * 512 + lane * 8];
            float4v z = {0.f, 0.f, 0.f, 0.f};
            s[kt] = __builtin_amdgcn_mfma_f32_16x16x32_bf16(kf, qf, z, 0, 0, 0);
        }

        float mx = fmaxf(fmaxf(s[0][0], s[0][1]), fmaxf(s[0][2], s[0][3]));
#pragma unroll
        for (int kt = 1; kt < 16; ++kt)
            mx = fmaxf(fmaxf(mx, s[kt][0]),
                       fmaxf(s[kt][1], fmaxf(s[kt][2], s[kt][3])));
        mx = fmaxf(mx, __shfl_xor(mx, 16));
        mx = fmaxf(mx, __shfl_xor(mx, 32));

        float nm = -mx * LOG2E;
        float l = 0.f;
#pragma unroll
        for (int kt = 0; kt < 16; ++kt) {
#pragma unroll
            for (int r = 0; r < 4; ++r) {
                float p = __builtin_amdgcn_exp2f(fmaf(s[kt][r], LOG2E, nm));
                s[kt][r] = p;
                l += p;
            }
        }
        l += __shfl_xor(l, 16);
        l += __shfl_xor(l, 32);
        float inv = __builtin_amdgcn_rcpf(l);

        float4v o0 = {0.f, 0.f, 0.f, 0.f}, o1 = {0.f, 0.f, 0.f, 0.f};
#pragma unroll
        for (int P = 0; P < 8; ++P) {
            union { u32 w[4]; short8v v; } pf;
            pf.w[0] = cvt_pk_bf16(s[2 * P][0],     s[2 * P][1]);
            pf.w[1] = cvt_pk_bf16(s[2 * P][2],     s[2 * P][3]);
            pf.w[2] = cvt_pk_bf16(s[2 * P + 1][0], s[2 * P + 1][1]);
            pf.w[3] = cvt_pk_bf16(s[2 * P + 1][2], s[2 * P + 1][3]);
            short8v v0 = *(const short8v*)&Vf[(P * 2 + 0) * 512 + lane * 8];
            short8v v1 = *(const short8v*)&Vf[(P * 2 + 1) * 512 + lane * 8];
            o0 = __builtin_amdgcn_mfma_f32_16x16x32_bf16(pf.v, v0, o0, 0, 0, 0);
            o1 = __builtin_amdgcn_mfma_f32_16x16x32_bf16(pf.v, v1, o1, 0, 0, 0);
        }

        int token0 = tb * 256 + rep * 64 + wave * 16;
#pragma unroll
        for (int r = 0; r < 4; ++r) {
            float invr = __shfl(inv, quad * 4 + r);
            u16* row = att + ((size_t)(b * N_TOK + token0 + quad * 4 + r)) * C_DIM + h * HD;
            row[ln]      = f2bf_hw(o0[r] * invr);
            row[16 + ln] = f2bf_hw(o1[r] * invr);
        }
    }
}

__global__ __launch_bounds__(256) void proj_res_mfma(
    const u16* __restrict__ att, const float* __restrict__ Wp,
    const u16* __restrict__ WpF, const float* __restrict__ bp,
    const float* __restrict__ x, float* __restrict__ y)
{
    __shared__ float Tf[C_DIM * 68];
    int b = blockIdx.x >> 8;
    int n0 = (blockIdx.x & 255) * 64;
    int t = threadIdx.x;
    int wv = t >> 6, lane = t & 63;
    int q8 = lane >> 4, ln = lane & 15;

    short8v Bf[18];
    if (WpF) {
#pragma unroll
        for (int i = 0; i < 18; ++i)
            Bf[i] = *(const short8v*)&WpF[(wv * 18 + i) * 512 + lane * 8];
    } else {
#pragma unroll
        for (int kt = 0; kt < 6; ++kt) {
#pragma unroll
            for (int jj = 0; jj < 3; ++jj) {
                const float* w0 = Wp + (kt * 32 + q8 * 8) * C_DIM + (wv * 3 + jj) * 16 + ln;
                union { u32 w[4]; short8v v; } f;
#pragma unroll
                for (int wj = 0; wj < 4; ++wj)
                    f.w[wj] = cvt_pk_bf16(w0[(2 * wj) * C_DIM], w0[(2 * wj + 1) * C_DIM]);
                Bf[kt * 3 + jj] = f.v;
            }
        }
    }

#pragma unroll
    for (int mt = 0; mt < 4; ++mt) {
        const u16* ab = att + ((size_t)(b * N_TOK + n0 + mt * 16 + ln)) * C_DIM + q8 * 8;
        float4v acc[3] = {{0.f,0.f,0.f,0.f},{0.f,0.f,0.f,0.f},{0.f,0.f,0.f,0.f}};
#pragma unroll
        for (int kt = 0; kt < 6; ++kt) {
            short8v a = *(const short8v*)(ab + kt * 32);
#pragma unroll
            for (int jj = 0; jj < 3; ++jj)
                acc[jj] = __builtin_amdgcn_mfma_f32_16x16x32_bf16(a, Bf[kt * 3 + jj], acc[jj], 0, 0, 0);
        }
#pragma unroll
        for (int jj = 0; jj < 3; ++jj)
#pragma unroll
            for (int r = 0; r < 4; ++r)
                Tf[((wv * 3 + jj) * 16 + ln) * 68 + mt * 16 + q8 * 4 + r] = acc[jj][r];
    }
    __syncthreads();

    {
        int r0 = t >> 4;
        int p  = t & 15;
#pragma unroll
        for (int pass = 0; pass < 12; ++pass) {
            int c = pass * 16 + r0;
            float bias = bp[c];
            float4 a = *(const float4*)&Tf[c * 68 + p * 4];
            const float4* xr = (const float4*)(x + (((size_t)(b * C_DIM + c)) << 14) + n0);
            float4*       yr = (float4*)(y + (((size_t)(b * C_DIM + c)) << 14) + n0);
            float4 u = xr[p];
            float4 w;
            w.x = a.x + bias + u.x;
            w.y = a.y + bias + u.y;
            w.z = a.z + bias + u.z;
            w.w = a.w + bias + u.w;
            yr[p] = w;
        }
    }
}

extern "C" void kernel_launch(void* const* d_in, const int* in_sizes, int n_in,
                              void* d_out, int out_size, void* d_ws, size_t ws_size,
                              hipStream_t stream) {
    const float* x     = (const float*)d_in[0];
    const float* prior = (const float*)d_in[1];
    const float* ln1_g = (const float*)d_in[2];
    const float* ln1_b = (const float*)d_in[3];
    const float* ln2_g = (const float*)d_in[4];
    const float* ln2_b = (const float*)d_in[5];
    const float* Wq    = (const float*)d_in[6];
    const float* Wkv   = (const float*)d_in[7];
    const float* Wp    = (const float*)d_in[8];
    const float* bp    = (const float*)d_in[9];

    char* outc = (char*)d_out;
    float* y = (float*)d_out;

    // Fused path ws layout:
    //   ws[0,        25165824): q bf16
    //   ws[25165824, +393216 ): KfG
    //   ws[+,        +393216 ): VfG
    //   ws[+,        +73728  ): WpF
    const size_t needF = 25165824ull + 393216ull + 393216ull + 73728ull;
    if (ws_size >= needF) {
        char* wsc = (char*)d_ws;
        u16* qb  = (u16*)wsc;
        u16* KfG = (u16*)(wsc + 25165824);
        u16* VfG = (u16*)(wsc + 25165824 + 393216);
        u16* WpF = (u16*)(wsc + 25165824 + 786432);
        u16* WqF = (u16*)outc;   // dead before y is written

        prep_combo<<<LN2_BLOCKS + 36, 256, 0, stream>>>(
            prior, ln2_g, ln2_b, Wkv, KfG, VfG, Wq, WqF, Wp, WpF);
        ln1_q_mfma<<<1024, 256, 0, stream>>>(x, ln1_g, ln1_b, WqF, qb);
        attn_proj_fused<<<1024, 384, 0, stream>>>(qb, KfG, VfG, WpF, bp, x, y);
    } else {
        // round-2 fallback layout
        u16*   qb   = (u16*)outc;
        u16*   WqF  = (u16*)(outc + 26738688);
        u16*   KfG  = (u16*)(outc + 26812416);
        u16*   VfG  = (u16*)(outc + 27205632);
        u16*   att  = (u16*)d_ws;
        bool has_wpf = ws_size >= 25165824ull + 73728ull;
        u16* WpF = has_wpf ? (u16*)((char*)d_ws + 25165824) : (u16*)nullptr;

        w_prep2<<<has_wpf ? 36 : 18, 256, 0, stream>>>(Wq, WqF, Wp, has_wpf ? WpF : WqF);
        ln1_q_mfma<<<1024, 256, 0, stream>>>(x, ln1_g, ln1_b, WqF, qb);
        ln2_kv_frag<<<1024, 192, 0, stream>>>(prior, ln2_g, ln2_b, Wkv, KfG, VfG);
        attn_mfma_kernel<<<1536, 256, 0, stream>>>(qb, KfG, VfG, att);
        proj_res_mfma<<<1024, 256, 0, stream>>>(att, Wp, WpF, bp, x, y);
    }
}

// Round 9
// 185.280 us; speedup vs baseline: 1.0487x; 1.0487x over previous
//
#include <hip/hip_runtime.h>

typedef unsigned short u16;
typedef unsigned int u32;

#define C_DIM 192
#define N_TOK 16384
#define M_LEN 256
#define HD 32
#define NH 6

#define AF_STRIDE 3080   // u16 per-token-tile A-frag region (6*512 + 8 skew)

typedef __attribute__((ext_vector_type(8))) short short8v;
typedef __attribute__((ext_vector_type(4))) float float4v;

// Hardware bf16 convert: 2 f32 -> packed 2x bf16 (RNE), 1 instruction.
__device__ __forceinline__ u32 cvt_pk_bf16(float lo, float hi) {
    u32 r;
    asm("v_cvt_pk_bf16_f32 %0, %1, %2" : "=v"(r) : "v"(lo), "v"(hi));
    return r;
}
__device__ __forceinline__ u16 f2bf_hw(float f) {
    return (u16)cvt_pk_bf16(f, f);
}

// ---- helper: fragment-prep for a 192x192 weight, parametrized thread base --
__device__ __forceinline__ void wprep_frag(
    const float* __restrict__ W, u16* __restrict__ outp, int gt)
{
    int f = gt >> 6, lane = gt & 63;
    int q8 = lane >> 4, ln = lane & 15;
    int wv = f / 18, r = f % 18;
    int kt = r / 3, jj = r % 3;
    const float* w0 = W + (kt * 32 + q8 * 8) * C_DIM + (wv * 3 + jj) * 16 + ln;
    union { u32 w[4]; short8v v; } out;
#pragma unroll
    for (int j = 0; j < 4; ++j)
        out.w[j] = cvt_pk_bf16(w0[(2 * j) * C_DIM], w0[(2 * j + 1) * C_DIM]);
    *(short8v*)&outp[f * 512 + lane * 8] = out.v;
}

// ---------------- Kernel W (fallback): Wq/Wp -> fragment-ordered bf16 ------
__global__ __launch_bounds__(256) void w_prep2(
    const float* __restrict__ Wq, u16* __restrict__ WqF,
    const float* __restrict__ Wp, u16* __restrict__ WpF)
{
    int bb = blockIdx.x;
    const float* W = (bb < 18) ? Wq : Wp;
    u16* outp = (bb < 18) ? WqF : WpF;
    wprep_frag(W, outp, (bb % 18) * 256 + threadIdx.x);
}

// ---------------- Kernel B+W: LN2+KV (1 row/block) + weight prep merged ----
// blocks [0,1024): ln2_kv, 1 row each (192 threads).
// blocks [1024,1072): weight-frag prep, 3 frags each (24 per matrix).
__global__ __launch_bounds__(192) void ln2_kv_wprep(
    const float* __restrict__ prior, const float* __restrict__ g,
    const float* __restrict__ beta, const float* __restrict__ Wkv,
    u16* __restrict__ KfG, u16* __restrict__ VfG,
    const float* __restrict__ Wq, u16* __restrict__ WqF,
    const float* __restrict__ Wp, u16* __restrict__ WpF)
{
    int tid = threadIdx.x;
    if (blockIdx.x >= 1024) {
        int bb = blockIdx.x - 1024;          // 0..47
        const float* W = (bb < 24) ? Wq : Wp;
        u16* outp = (bb < 24) ? WqF : WpF;
        wprep_frag(W, outp, (bb % 24) * 192 + tid);   // frags bbm*3..bbm*3+2
        return;
    }
    __shared__ float pr[C_DIM];
    __shared__ float red[3][2];
    int row = blockIdx.x;
    int wv = tid >> 6;
    float val = prior[row * C_DIM + tid];
    float s1 = val, s2 = val * val;
#pragma unroll
    for (int m = 1; m < 64; m <<= 1) {
        s1 += __shfl_xor(s1, m);
        s2 += __shfl_xor(s2, m);
    }
    if ((tid & 63) == 0) { red[wv][0] = s1; red[wv][1] = s2; }
    __syncthreads();
    float a  = red[0][0] + red[1][0] + red[2][0];
    float c2 = red[0][1] + red[1][1] + red[2][1];
    float mu = a * (1.f / C_DIM);
    float rs = rsqrtf(c2 * (1.f / C_DIM) - mu * mu + 1e-5f);
    pr[tid] = (val - mu) * rs * g[tid] + beta[tid];
    __syncthreads();
    float ka = 0.f, va = 0.f;
    for (int c = 0; c < C_DIM; ++c) {
        float p = pr[c];
        ka += p * Wkv[c * 384 + tid];
        va += p * Wkv[c * 384 + 192 + tid];
    }
    int b = row >> 8, m = row & 255;
    int h = tid >> 5, dim = tid & 31;
    int bh = b * NH + h;
    int kt = m >> 4, r = m & 15;
    {
        int qd = dim >> 3, j = dim & 7;
        KfG[bh * 8192 + kt * 512 + (qd * 16 + r) * 8 + j] =
            f2bf_hw(ka * 0.17677669529663687f);
    }
    {
        int qd = r >> 2, reg = r & 3;
        int P = kt >> 1;
        int j = reg + 4 * (kt & 1);
        int dh = dim >> 4, n = dim & 15;
        VfG[bh * 8192 + (P * 2 + dh) * 512 + (qd * 16 + n) * 8 + j] = f2bf_hw(va);
    }
}

// ---------------- Kernel A: LN1 + Q projection via MFMA ----------------
__global__ __launch_bounds__(256) void ln1_q_mfma(
    const float* __restrict__ x, const float* __restrict__ g,
    const float* __restrict__ beta, const u16* __restrict__ WqF,
    u16* __restrict__ q)
{
    __shared__ u16 Af[4 * AF_STRIDE];
    __shared__ u16 Tq[64 * 200];
    __shared__ float part[64][4][2];
    __shared__ float mu_s[64], rs_s[64];
    int b = blockIdx.x >> 8;
    int n0 = (blockIdx.x & 255) * 64;
    int t = threadIdx.x;
    int wv = t >> 6, lane = t & 63;

    float xv[48];
    {
        const float* xb = x + (((size_t)(b * C_DIM + wv * 48)) << 14) + n0 + lane;
        float s1p[4] = {0,0,0,0}, s2p[4] = {0,0,0,0};
#pragma unroll
        for (int i = 0; i < 48; ++i) {
            float f = xb[(size_t)i << 14];
            xv[i] = f;
            s1p[i & 3] += f;
            s2p[i & 3] += f * f;
        }
        part[lane][wv][0] = (s1p[0] + s1p[1]) + (s1p[2] + s1p[3]);
        part[lane][wv][1] = (s2p[0] + s2p[1]) + (s2p[2] + s2p[3]);
    }
    __syncthreads();
    if (t < 64) {
        float a  = part[t][0][0] + part[t][1][0] + part[t][2][0] + part[t][3][0];
        float c2 = part[t][0][1] + part[t][1][1] + part[t][2][1] + part[t][3][1];
        float mu = a * (1.f / C_DIM);
        mu_s[t] = mu;
        rs_s[t] = rsqrtf(c2 * (1.f / C_DIM) - mu * mu + 1e-5f);
    }
    __syncthreads();

    {
        float mu = mu_s[lane], rs = rs_s[lane];
        int mt2 = lane >> 4, ln2 = lane & 15;
        u32* A32 = (u32*)Af;
#pragma unroll
        for (int i = 0; i < 48; i += 2) {
            int c = wv * 48 + i;
            float f0 = (xv[i]     - mu) * rs * g[c]     + beta[c];
            float f1 = (xv[i + 1] - mu) * rs * g[c + 1] + beta[c + 1];
            int kt = c >> 5, k8 = (c & 31) >> 3, j = c & 7;
            A32[(mt2 * AF_STRIDE + kt * 512 + k8 * 128 + ln2 * 8 + j) >> 1] =
                cvt_pk_bf16(f0, f1);
        }
    }
    __syncthreads();

    int q8 = lane >> 4, ln = lane & 15;
    short8v Bf[18];
#pragma unroll
    for (int i = 0; i < 18; ++i)
        Bf[i] = *(const short8v*)&WqF[(wv * 18 + i) * 512 + lane * 8];

#pragma unroll
    for (int mt = 0; mt < 4; ++mt) {
        float4v acc[3] = {{0.f,0.f,0.f,0.f},{0.f,0.f,0.f,0.f},{0.f,0.f,0.f,0.f}};
#pragma unroll
        for (int kt = 0; kt < 6; ++kt) {
            short8v a = *(const short8v*)&Af[mt * AF_STRIDE + kt * 512 + lane * 8];
#pragma unroll
            for (int jj = 0; jj < 3; ++jj)
                acc[jj] = __builtin_amdgcn_mfma_f32_16x16x32_bf16(a, Bf[kt * 3 + jj], acc[jj], 0, 0, 0);
        }
#pragma unroll
        for (int jj = 0; jj < 3; ++jj)
#pragma unroll
            for (int r = 0; r < 4; ++r)
                Tq[(mt * 16 + q8 * 4 + r) * 200 + (wv * 3 + jj) * 16 + ln] = f2bf_hw(acc[jj][r]);
    }
    __syncthreads();

    {
        int tok = t >> 2, pp = t & 3;
        const uint4* src = (const uint4*)&Tq[tok * 200 + pp * 48];
        uint4* dst = (uint4*)(q + ((size_t)(b * N_TOK + n0 + tok)) * C_DIM + pp * 48);
#pragma unroll
        for (int i = 0; i < 6; ++i) dst[i] = src[i];
    }
}

// ---------------- Kernel B (fallback): LN2+KV, 1 row/block -----------------
__global__ __launch_bounds__(192) void ln2_kv_frag(
    const float* __restrict__ prior, const float* __restrict__ g,
    const float* __restrict__ beta, const float* __restrict__ Wkv,
    u16* __restrict__ KfG, u16* __restrict__ VfG)
{
    __shared__ float pr[C_DIM];
    __shared__ float red[3][2];
    int row = blockIdx.x;
    int tid = threadIdx.x;
    int wv = tid >> 6;
    float val = prior[row * C_DIM + tid];
    float s1 = val, s2 = val * val;
#pragma unroll
    for (int m = 1; m < 64; m <<= 1) {
        s1 += __shfl_xor(s1, m);
        s2 += __shfl_xor(s2, m);
    }
    if ((tid & 63) == 0) { red[wv][0] = s1; red[wv][1] = s2; }
    __syncthreads();
    float a  = red[0][0] + red[1][0] + red[2][0];
    float c2 = red[0][1] + red[1][1] + red[2][1];
    float mu = a * (1.f / C_DIM);
    float rs = rsqrtf(c2 * (1.f / C_DIM) - mu * mu + 1e-5f);
    pr[tid] = (val - mu) * rs * g[tid] + beta[tid];
    __syncthreads();
    float ka = 0.f, va = 0.f;
    for (int c = 0; c < C_DIM; ++c) {
        float p = pr[c];
        ka += p * Wkv[c * 384 + tid];
        va += p * Wkv[c * 384 + 192 + tid];
    }
    int b = row >> 8, m = row & 255;
    int h = tid >> 5, dim = tid & 31;
    int bh = b * NH + h;
    int kt = m >> 4, r = m & 15;
    {
        int qd = dim >> 3, j = dim & 7;
        KfG[bh * 8192 + kt * 512 + (qd * 16 + r) * 8 + j] =
            f2bf_hw(ka * 0.17677669529663687f);
    }
    {
        int qd = r >> 2, reg = r & 3;
        int P = kt >> 1;
        int j = reg + 4 * (kt & 1);
        int dh = dim >> 4, n = dim & 15;
        VfG[bh * 8192 + (P * 2 + dh) * 512 + (qd * 16 + n) * 8 + j] = f2bf_hw(va);
    }
}

// ---------------- Kernel C+D fused v4 (r6, verified): K/V in registers -----
// grid: 1024 (b x 64-token tiles), 384 threads (6 waves; wave w = head w).
// __launch_bounds__(384,2): 256-reg cap, zero spill (VGPR 124 measured).
__global__ __launch_bounds__(384, 2) void attn_proj_fused(
    const u16* __restrict__ q, const u16* __restrict__ KfG,
    const u16* __restrict__ VfG, const u16* __restrict__ WpF,
    const float* __restrict__ bp, const float* __restrict__ x,
    float* __restrict__ y)
{
    __shared__ float Tf[C_DIM * 68];       // 52224 B; first 25600 B alias att tile
    u16* att_lds = (u16*)Tf;               // [64 tokens][stride 200] u16
    int b  = blockIdx.x >> 8;
    int n0 = (blockIdx.x & 255) * 64;
    int t = threadIdx.x;
    int wave = t >> 6, lane = t & 63;      // wave = head (0..5)
    int quad = lane >> 4, ln = lane & 15;
    const float LOG2E = 1.4426950408889634f;

    // ---- prologue: K/V fragments of THIS wave's head into registers ----
    int h = wave;
    short8v k_r[16], v_r[16];
    {
        const u16* Kf = KfG + (b * NH + h) * 8192;
        const u16* Vf = VfG + (b * NH + h) * 8192;
#pragma unroll
        for (int kt = 0; kt < 16; ++kt)
            k_r[kt] = *(const short8v*)&Kf[kt * 512 + lane * 8];
#pragma unroll
        for (int kt = 0; kt < 16; ++kt)
            v_r[kt] = *(const short8v*)&Vf[kt * 512 + lane * 8];
    }

    // ---- attention phase: 4 reps x 16 tokens, all state in registers ----
    {
        const u16* qbase = q + ((size_t)(b * N_TOK + n0 + ln)) * C_DIM + h * HD + quad * 8;
        short8v qnext = *(const short8v*)qbase;   // rep-0 prefetch

        for (int rep = 0; rep < 4; ++rep) {
            short8v qf = qnext;
            int nrep = rep < 3 ? rep + 1 : 3;
            qnext = *(const short8v*)(qbase + (size_t)nrep * 16 * C_DIM);

            float4v s[16];
#pragma unroll
            for (int kt = 0; kt < 16; ++kt) {
                float4v z = {0.f, 0.f, 0.f, 0.f};
                s[kt] = __builtin_amdgcn_mfma_f32_16x16x32_bf16(k_r[kt], qf, z, 0, 0, 0);
            }

            float mx = fmaxf(fmaxf(s[0][0], s[0][1]), fmaxf(s[0][2], s[0][3]));
#pragma unroll
            for (int kt = 1; kt < 16; ++kt)
                mx = fmaxf(fmaxf(mx, s[kt][0]),
                           fmaxf(s[kt][1], fmaxf(s[kt][2], s[kt][3])));
            mx = fmaxf(mx, __shfl_xor(mx, 16));
            mx = fmaxf(mx, __shfl_xor(mx, 32));

            float nm = -mx * LOG2E;
            float l = 0.f;
#pragma unroll
            for (int kt = 0; kt < 16; ++kt) {
#pragma unroll
                for (int r = 0; r < 4; ++r) {
                    float p = __builtin_amdgcn_exp2f(fmaf(s[kt][r], LOG2E, nm));
                    s[kt][r] = p;
                    l += p;
                }
            }
            l += __shfl_xor(l, 16);
            l += __shfl_xor(l, 32);
            float inv = __builtin_amdgcn_rcpf(l);

            float4v o0 = {0.f, 0.f, 0.f, 0.f}, o1 = {0.f, 0.f, 0.f, 0.f};
#pragma unroll
            for (int P = 0; P < 8; ++P) {
                union { u32 w[4]; short8v v; } pf;
                pf.w[0] = cvt_pk_bf16(s[2 * P][0],     s[2 * P][1]);
                pf.w[1] = cvt_pk_bf16(s[2 * P][2],     s[2 * P][3]);
                pf.w[2] = cvt_pk_bf16(s[2 * P + 1][0], s[2 * P + 1][1]);
                pf.w[3] = cvt_pk_bf16(s[2 * P + 1][2], s[2 * P + 1][3]);
                o0 = __builtin_amdgcn_mfma_f32_16x16x32_bf16(pf.v, v_r[2 * P],     o0, 0, 0, 0);
                o1 = __builtin_amdgcn_mfma_f32_16x16x32_bf16(pf.v, v_r[2 * P + 1], o1, 0, 0, 0);
            }

#pragma unroll
            for (int r = 0; r < 4; ++r) {
                float invr = __shfl(inv, quad * 4 + r);
                u16* rw = &att_lds[(rep * 16 + quad * 4 + r) * 200 + h * HD];
                rw[ln]      = f2bf_hw(o0[r] * invr);
                rw[16 + ln] = f2bf_hw(o1[r] * invr);
            }
        }
    }
    __syncthreads();

    // ---- x prefetch for epilogue (K/V regs dead; 32 regs free) ----
    float4 xu[8];
    {
        int r0 = t >> 4, p = t & 15;
#pragma unroll
        for (int pass = 0; pass < 8; ++pass) {
            int c = pass * 24 + r0;
            xu[pass] = ((const float4*)(x + (((size_t)(b * C_DIM + c)) << 14) + n0))[p];
        }
    }

    // ---- proj MFMA phase: wave w owns column-frags {2w, 2w+1} x 4 token-tiles
    short8v Bf[12];
#pragma unroll
    for (int jc = 0; jc < 2; ++jc) {
        int cf = wave * 2 + jc;            // 0..11
        int wv = cf / 3, jj = cf % 3;
#pragma unroll
        for (int kt = 0; kt < 6; ++kt)
            Bf[jc * 6 + kt] = *(const short8v*)&WpF[(wv * 18 + kt * 3 + jj) * 512 + lane * 8];
    }

    float4v acc[4][2];
#pragma unroll
    for (int mt = 0; mt < 4; ++mt) {
#pragma unroll
        for (int jc = 0; jc < 2; ++jc) {
            float4v z = {0.f, 0.f, 0.f, 0.f};
            acc[mt][jc] = z;
        }
#pragma unroll
        for (int kt = 0; kt < 6; ++kt) {
            short8v a = *(const short8v*)&att_lds[(mt * 16 + ln) * 200 + quad * 8 + kt * 32];
#pragma unroll
            for (int jc = 0; jc < 2; ++jc)
                acc[mt][jc] = __builtin_amdgcn_mfma_f32_16x16x32_bf16(a, Bf[jc * 6 + kt], acc[mt][jc], 0, 0, 0);
        }
    }
    __syncthreads();   // att tile dead; region reused as Tf

#pragma unroll
    for (int mt = 0; mt < 4; ++mt)
#pragma unroll
        for (int jc = 0; jc < 2; ++jc) {
            int c = (wave * 2 + jc) * 16 + ln;
#pragma unroll
            for (int r = 0; r < 4; ++r)
                Tf[c * 68 + mt * 16 + quad * 4 + r] = acc[mt][jc][r];
        }
    __syncthreads();

    // ---- epilogue: 384 threads, 8 passes x 24 channels, coalesced ----
    {
        int r0 = t >> 4;      // 0..23
        int p  = t & 15;
#pragma unroll
        for (int pass = 0; pass < 8; ++pass) {
            int c = pass * 24 + r0;
            float bias = bp[c];
            float4 a = *(const float4*)&Tf[c * 68 + p * 4];
            float4*       yr = (float4*)(y + (((size_t)(b * C_DIM + c)) << 14) + n0);
            float4 u = xu[pass];
            float4 w;
            w.x = a.x + bias + u.x;
            w.y = a.y + bias + u.y;
            w.z = a.z + bias + u.z;
            w.w = a.w + bias + u.w;
            yr[p] = w;
        }
    }
}

// ---------------- Fallback kernels (round-2 pipeline) ----------------
__global__ __launch_bounds__(256) void attn_mfma_kernel(
    const u16* __restrict__ q, const u16* __restrict__ KfG,
    const u16* __restrict__ VfG, u16* __restrict__ att)
{
    __shared__ u16 sh[16384];
    int tb = blockIdx.x & 63;
    int bh = blockIdx.x >> 6;
    int h = bh % NH, b = bh / NH;
    int tid = threadIdx.x;
    int wave = tid >> 6, lane = tid & 63;
    int quad = lane >> 4, ln = lane & 15;

    const u16* qbase = q + ((size_t)(b * N_TOK + tb * 256 + wave * 16 + ln)) * C_DIM
                         + h * HD + quad * 8;
    short8v qnext = *(const short8v*)qbase;

    {
        const uint4* Ks = (const uint4*)(KfG + bh * 8192);
        const uint4* Vs = (const uint4*)(VfG + bh * 8192);
        uint4* d = (uint4*)sh;
#pragma unroll
        for (int i = tid; i < 2048; i += 256)
            d[i] = (i < 1024) ? Ks[i] : Vs[i - 1024];
    }
    __syncthreads();

    const u16* Kf = sh;
    const u16* Vf = sh + 8192;
    const float LOG2E = 1.4426950408889634f;

    for (int rep = 0; rep < 4; ++rep) {
        short8v qf = qnext;
        int nrep = rep < 3 ? rep + 1 : 3;
        qnext = *(const short8v*)(qbase + (size_t)nrep * 64 * C_DIM);

        float4v s[16];
#pragma unroll
        for (int kt = 0; kt < 16; ++kt) {
            short8v kf = *(const short8v*)&Kf[kt * 512 + lane * 8];
            float4v z = {0.f, 0.f, 0.f, 0.f};
            s[kt] = __builtin_amdgcn_mfma_f32_16x16x32_bf16(kf, qf, z, 0, 0, 0);
        }

        float mx = fmaxf(fmaxf(s[0][0], s[0][1]), fmaxf(s[0][2], s[0][3]));
#pragma unroll
        for (int kt = 1; kt < 16; ++kt)
            mx = fmaxf(fmaxf(mx, s[kt][0]),
                       fmaxf(s[kt][1], fmaxf(s[kt][2], s[kt][3])));
        mx = fmaxf(mx, __shfl_xor(mx, 16));
        mx = fmaxf(mx, __shfl_xor(mx, 32));

        float nm = -mx * LOG2E;
        float l = 0.f;
#pragma unroll
        for (int kt = 0; kt < 16; ++kt) {
#pragma unroll
            for (int r = 0; r < 4; ++r) {
                float p = __builtin_amdgcn_exp2f(fmaf(s[kt][r], LOG2E, nm));
                s[kt][r] = p;
                l += p;
            }
        }
        l += __shfl_xor(l, 16);
        l += __shfl_xor(l, 32);
        float inv = __builtin_amdgcn_rcpf(l);

        float4v o0 = {0.f, 0.f, 0.f, 0.f}, o1 = {0.f, 0.f, 0.f, 0.f};
#pragma unroll
        for (int P = 0; P < 8; ++P) {
            union { u32 w[4]; short8v v; } pf;
            pf.w[0] = cvt_pk_bf16(s[2 * P][0],     s[2 * P][1]);
            pf.w[1] = cvt_pk_bf16(s[2 * P][2],     s[2 * P][3]);
            pf.w[2] = cvt_pk_bf16(s[2 * P + 1][0], s[2 * P + 1][1]);
            pf.w[3] = cvt_pk_bf16(s[2 * P + 1][2], s[2 * P + 1][3]);
            short8v v0 = *(const short8v*)&Vf[(P * 2 + 0) * 512 + lane * 8];
            short8v v1 = *(const short8v*)&Vf[(P * 2 + 1) * 512 + lane * 8];
            o0 = __builtin_amdgcn_mfma_f32_16x16x32_bf16(pf.v, v0, o0, 0, 0, 0);
            o1 = __builtin_amdgcn_mfma_f32_16x16x32_bf16(pf.v, v1, o1, 0, 0, 0);
        }

        int token0 = tb * 256 + rep * 64 + wave * 16;
#pragma unroll
        for (int r = 0; r < 4; ++r) {
            float invr = __shfl(inv, quad * 4 + r);
            u16* row = att + ((size_t)(b * N_TOK + token0 + quad * 4 + r)) * C_DIM + h * HD;
            row[ln]      = f2bf_hw(o0[r] * invr);
            row[16 + ln] = f2bf_hw(o1[r] * invr);
        }
    }
}

__global__ __launch_bounds__(256) void proj_res_mfma(
    const u16* __restrict__ att, const float* __restrict__ Wp,
    const u16* __restrict__ WpF, const float* __restrict__ bp,
    const float* __restrict__ x, float* __restrict__ y)
{
    __shared__ float Tf[C_DIM * 68];
    int b = blockIdx.x >> 8;
    int n0 = (blockIdx.x & 255) * 64;
    int t = threadIdx.x;
    int wv = t >> 6, lane = t & 63;
    int q8 = lane >> 4, ln = lane & 15;

    short8v Bf[18];
    if (WpF) {
#pragma unroll
        for (int i = 0; i < 18; ++i)
            Bf[i] = *(const short8v*)&WpF[(wv * 18 + i) * 512 + lane * 8];
    } else {
#pragma unroll
        for (int kt = 0; kt < 6; ++kt) {
#pragma unroll
            for (int jj = 0; jj < 3; ++jj) {
                const float* w0 = Wp + (kt * 32 + q8 * 8) * C_DIM + (wv * 3 + jj) * 16 + ln;
                union { u32 w[4]; short8v v; } f;
#pragma unroll
                for (int wj = 0; wj < 4; ++wj)
                    f.w[wj] = cvt_pk_bf16(w0[(2 * wj) * C_DIM], w0[(2 * wj + 1) * C_DIM]);
                Bf[kt * 3 + jj] = f.v;
            }
        }
    }

#pragma unroll
    for (int mt = 0; mt < 4; ++mt) {
        const u16* ab = att + ((size_t)(b * N_TOK + n0 + mt * 16 + ln)) * C_DIM + q8 * 8;
        float4v acc[3] = {{0.f,0.f,0.f,0.f},{0.f,0.f,0.f,0.f},{0.f,0.f,0.f,0.f}};
#pragma unroll
        for (int kt = 0; kt < 6; ++kt) {
            short8v a = *(const short8v*)(ab + kt * 32);
#pragma unroll
            for (int jj = 0; jj < 3; ++jj)
                acc[jj] = __builtin_amdgcn_mfma_f32_16x16x32_bf16(a, Bf[kt * 3 + jj], acc[jj], 0, 0, 0);
        }
#pragma unroll
        for (int jj = 0; jj < 3; ++jj)
#pragma unroll
            for (int r = 0; r < 4; ++r)
                Tf[((wv * 3 + jj) * 16 + ln) * 68 + mt * 16 + q8 * 4 + r] = acc[jj][r];
    }
    __syncthreads();

    {
        int r0 = t >> 4;
        int p  = t & 15;
#pragma unroll
        for (int pass = 0; pass < 12; ++pass) {
            int c = pass * 16 + r0;
            float bias = bp[c];
            float4 a = *(const float4*)&Tf[c * 68 + p * 4];
            const float4* xr = (const float4*)(x + (((size_t)(b * C_DIM + c)) << 14) + n0);
            float4*       yr = (float4*)(y + (((size_t)(b * C_DIM + c)) << 14) + n0);
            float4 u = xr[p];
            float4 w;
            w.x = a.x + bias + u.x;
            w.y = a.y + bias + u.y;
            w.z = a.z + bias + u.z;
            w.w = a.w + bias + u.w;
            yr[p] = w;
        }
    }
}

extern "C" void kernel_launch(void* const* d_in, const int* in_sizes, int n_in,
                              void* d_out, int out_size, void* d_ws, size_t ws_size,
                              hipStream_t stream) {
    const float* x     = (const float*)d_in[0];
    const float* prior = (const float*)d_in[1];
    const float* ln1_g = (const float*)d_in[2];
    const float* ln1_b = (const float*)d_in[3];
    const float* ln2_g = (const float*)d_in[4];
    const float* ln2_b = (const float*)d_in[5];
    const float* Wq    = (const float*)d_in[6];
    const float* Wkv   = (const float*)d_in[7];
    const float* Wp    = (const float*)d_in[8];
    const float* bp    = (const float*)d_in[9];

    char* outc = (char*)d_out;
    float* y = (float*)d_out;

    // Fused (r6) path ws layout:
    //   ws[0,        25165824): q bf16
    //   ws[25165824, +393216 ): KfG
    //   ws[+,        +393216 ): VfG
    //   ws[+,        +73728  ): WqF
    //   ws[+,        +73728  ): WpF
    const size_t needF = 25165824ull + 393216ull * 2 + 73728ull * 2;
    if (ws_size >= needF) {
        char* wsc = (char*)d_ws;
        u16* qb  = (u16*)wsc;
        u16* KfG = (u16*)(wsc + 25165824);
        u16* VfG = (u16*)(wsc + 25165824 + 393216);
        u16* WqF = (u16*)(wsc + 25165824 + 786432);
        u16* WpF = (u16*)(wsc + 25165824 + 786432 + 73728);

        ln2_kv_wprep<<<1072, 192, 0, stream>>>(
            prior, ln2_g, ln2_b, Wkv, KfG, VfG, Wq, WqF, Wp, WpF);
        ln1_q_mfma<<<1024, 256, 0, stream>>>(x, ln1_g, ln1_b, WqF, qb);
        attn_proj_fused<<<1024, 384, 0, stream>>>(qb, KfG, VfG, WpF, bp, x, y);
    } else {
        // round-2 fallback layout
        u16*   qb   = (u16*)outc;
        u16*   WqF  = (u16*)(outc + 26738688);
        u16*   KfG  = (u16*)(outc + 26812416);
        u16*   VfG  = (u16*)(outc + 27205632);
        u16*   att  = (u16*)d_ws;
        bool has_wpf = ws_size >= 25165824ull + 73728ull;
        u16* WpF = has_wpf ? (u16*)((char*)d_ws + 25165824) : (u16*)nullptr;

        w_prep2<<<has_wpf ? 36 : 18, 256, 0, stream>>>(Wq, WqF, Wp, has_wpf ? WpF : WqF);
        ln1_q_mfma<<<1024, 256, 0, stream>>>(x, ln1_g, ln1_b, WqF, qb);
        ln2_kv_frag<<<1024, 192, 0, stream>>>(prior, ln2_g, ln2_b, Wkv, KfG, VfG);
        attn_mfma_kernel<<<1536, 256, 0, stream>>>(qb, KfG, VfG, att);
        proj_res_mfma<<<1024, 256, 0, stream>>>(att, Wp, WpF, bp, x, y);
    }
}